// Round 2
// baseline (2317.104 us; speedup 1.0000x reference)
//
#include <hip/hip_runtime.h>
#include <math.h>

#define Nn 512
#define Mm 32000
#define Bb 64
#define Tt 256

typedef short v8s __attribute__((ext_vector_type(8)));   // 8 bf16 (4 VGPR) MFMA frag
typedef float v4f __attribute__((ext_vector_type(4)));   // MFMA accumulator
typedef unsigned short us4 __attribute__((ext_vector_type(4)));
typedef float f4 __attribute__((ext_vector_type(4)));

__device__ inline unsigned short f2bf(float f) {  // RNE float->bf16
  unsigned int u = __float_as_uint(f);
  unsigned int r = u + 0x7FFFu + ((u >> 16) & 1u);
  return (unsigned short)(r >> 16);
}

// ---- colsum[k] = sum_j exp(trans[j][k]); inputs ~N(0,1) so exp never overflows ----
__global__ void k_colsum(const float* __restrict__ trans, float* __restrict__ colsum) {
  int tid = threadIdx.x;
  int j0 = blockIdx.x * 16;
  float a0 = 0.f, a1 = 0.f;
  for (int r = 0; r < 16; ++r) {
    a0 += __expf(trans[(j0 + r) * Nn + tid]);
    a1 += __expf(trans[(j0 + r) * Nn + 256 + tid]);
  }
  atomicAdd(&colsum[tid], a0);
  atomicAdd(&colsum[256 + tid], a1);
}

// ---- A[j][k] = exp(trans[j][k]) / colsum[k], bf16 row-major ----
__global__ void k_writeA(const float* __restrict__ trans, const float* __restrict__ colsum,
                         unsigned short* __restrict__ Abf) {
  int i = blockIdx.x * 256 + threadIdx.x;   // 1024 blocks x 256 = 262144
  float v = __expf(trans[i]) / colsum[i & (Nn - 1)];
  Abf[i] = f2bf(v);
}

// ---- pi = softmax(prior), no max pass needed ----
__global__ void k_pi(const float* __restrict__ prior, float* __restrict__ pi) {
  int tid = threadIdx.x;
  __shared__ float sm[512];
  float e = __expf(prior[tid]);
  sm[tid] = e; __syncthreads();
  for (int off = 256; off; off >>= 1) { if (tid < off) sm[tid] += sm[tid + off]; __syncthreads(); }
  pi[tid] = e / sm[0];
}

// ---- row-sum of exp(emis) + gather: Pem[t][j][b] = exp(emis[j,x[b,t]]) / rowsum ----
__global__ void k_emis(const float* __restrict__ emis, const int* __restrict__ x,
                       float* __restrict__ Pem) {
  int j = blockIdx.x, tid = threadIdx.x;
  const float* row = emis + (size_t)j * Mm;
  const f4* row4 = (const f4*)row;
  float s = 0.f;
  for (int i = tid; i < Mm / 4; i += 256) {            // 8000 float4 chunks
    f4 v = row4[i];
    s += __expf(v.x) + __expf(v.y) + __expf(v.z) + __expf(v.w);
  }
  __shared__ float ss[256];
  ss[tid] = s; __syncthreads();
  for (int off = 128; off; off >>= 1) { if (tid < off) ss[tid] += ss[tid + off]; __syncthreads(); }
  float rs = 1.f / ss[0];
  for (int r = 0; r < (Bb * Tt) / 256; ++r) {
    int idx = r * 256 + tid;
    int t = idx >> 6, b = idx & 63;
    int mv = x[b * Tt + t];
    Pem[(size_t)t * (Nn * Bb) + j * Bb + b] = __expf(row[mv]) * rs;
  }
}

// ---- recursion: 4 independent blocks (16 batch cols each), 8 waves x 64 rows of A in VGPRs,
// ---- alpha lives in LDS only; one __syncthreads per step; no grid sync ----
__global__ __launch_bounds__(512, 1) void k_fwd(
    const unsigned short* __restrict__ Abf, const float* __restrict__ Pem,
    const float* __restrict__ pi, const int* __restrict__ Tlen,
    float* __restrict__ out)
{
  __shared__ __align__(16) unsigned short ybuf[2][16 * Nn];  // [c][k] bf16, XOR-swizzled; 32 KB
  const int g = blockIdx.x;                 // batch cols g*16 .. g*16+15
  const int tid = threadIdx.x;
  const int w = tid >> 6, lane = tid & 63;
  const int c = lane & 15, kq = lane >> 4;  // MFMA lane coords
  const int jw = w * 64;                    // this wave's 64 A-rows
  char* y0p = (char*)&ybuf[0][0];
  char* y1p = (char*)&ybuf[1][0];
  const int swz = (c & 7) << 4;

  // A fragments: af[rt][kk] -> lane holds A[jw + rt*16 + c][kk*32 + kq*8 + e]
  v8s af[4][16];
  #pragma unroll
  for (int rt = 0; rt < 4; ++rt)
    #pragma unroll
    for (int kk = 0; kk < 16; ++kk)
      af[rt][kk] = *reinterpret_cast<const v8s*>(Abf + (size_t)(jw + rt * 16 + c) * Nn + kk * 32 + kq * 8);

  v8s onef;
  #pragma unroll
  for (int e = 0; e < 8; ++e) onef[e] = (short)0x3F80;  // bf16 1.0

  const int b = g * 16 + c;
  const int Tb = Tlen[b];
  float L = 0.f;

  // init: y0[j][c'] = Pem[0][j][g*16+c'] * pi[j]  (thread: c'=tid&15, 16 consecutive j)
  {
    int cc = tid & 15, jb = (tid >> 4) * 16, sz = (cc & 7) << 4;
    #pragma unroll
    for (int r = 0; r < 16; r += 4) {
      us4 v;
      #pragma unroll
      for (int q = 0; q < 4; ++q) {
        int j = jb + r + q;
        v[q] = f2bf(Pem[(size_t)j * Bb + g * 16 + cc] * pi[j]);
      }
      *reinterpret_cast<us4*>(y0p + ((cc * 1024 + (jb + r) * 2) ^ sz)) = v;
    }
  }
  __syncthreads();

  int p = 0;
  for (int t = 1; t <= Tt; ++t) {
    // issue Pem loads early (consumed in epilogue, hidden under MFMAs)
    float pem[4][4];
    if (t < Tt) {
      #pragma unroll
      for (int rt = 0; rt < 4; ++rt)
        #pragma unroll
        for (int r = 0; r < 4; ++r)
          pem[rt][r] = Pem[(size_t)t * (Nn * Bb) + (size_t)(jw + rt * 16 + kq * 4 + r) * Bb + b];
    }

    // B fragments from LDS (swizzled): lane holds y[kk*32+kq*8+e][c]
    char* rp = p ? y1p : y0p;
    v8s bfr[16];
    #pragma unroll
    for (int kk = 0; kk < 16; ++kk)
      bfr[kk] = *reinterpret_cast<const v8s*>(rp + ((c * 1024 + (kk * 32 + kq * 8) * 2) ^ swz));

    v4f accs = {0.f, 0.f, 0.f, 0.f};
    v4f acc[4];
    #pragma unroll
    for (int rt = 0; rt < 4; ++rt) acc[rt] = (v4f){0.f, 0.f, 0.f, 0.f};

    if (t < Tt) {
      #pragma unroll
      for (int kk = 0; kk < 16; ++kk) {
        accs   = __builtin_amdgcn_mfma_f32_16x16x32_bf16(onef,      bfr[kk], accs,   0, 0, 0);
        acc[0] = __builtin_amdgcn_mfma_f32_16x16x32_bf16(af[0][kk], bfr[kk], acc[0], 0, 0, 0);
        acc[1] = __builtin_amdgcn_mfma_f32_16x16x32_bf16(af[1][kk], bfr[kk], acc[1], 0, 0, 0);
        acc[2] = __builtin_amdgcn_mfma_f32_16x16x32_bf16(af[2][kk], bfr[kk], acc[2], 0, 0, 0);
        acc[3] = __builtin_amdgcn_mfma_f32_16x16x32_bf16(af[3][kk], bfr[kk], acc[3], 0, 0, 0);
      }
    } else {
      #pragma unroll
      for (int kk = 0; kk < 16; ++kk)
        accs = __builtin_amdgcn_mfma_f32_16x16x32_bf16(onef, bfr[kk], accs, 0, 0, 0);
    }

    // s_{t-1} = sum_k y_{t-1}[k, c]  (all acc rows equal for ones-A; col = c)
    float s = accs[0];
    L += __logf(s);                       // L = sum_{tau<=t-1} log s_tau = log_sums[b][t-1]
    if (w == 0 && kq == 0 && Tb == t) out[b] = L;
    if (t == Tt) break;

    // epilogue: y_t[row][c] = acc * Pem_t * (1/s_{t-1}), bf16, to other LDS buffer
    float inv = 1.f / s;
    char* wp = p ? y0p : y1p;
    #pragma unroll
    for (int rt = 0; rt < 4; ++rt) {
      us4 vv;
      #pragma unroll
      for (int r = 0; r < 4; ++r) vv[r] = f2bf(acc[rt][r] * pem[rt][r] * inv);
      int k0 = jw + rt * 16 + kq * 4;
      *reinterpret_cast<us4*>(wp + ((c * 1024 + k0 * 2) ^ swz)) = vv;
    }
    p ^= 1;
    __syncthreads();
  }
}

extern "C" void kernel_launch(void* const* d_in, const int* in_sizes, int n_in,
                              void* d_out, int out_size, void* d_ws, size_t ws_size,
                              hipStream_t stream) {
  const int*   x     = (const int*)  d_in[0];
  const int*   Tlen  = (const int*)  d_in[1];
  const float* trans = (const float*)d_in[2];
  const float* emis  = (const float*)d_in[3];
  const float* prior = (const float*)d_in[4];
  float* out = (float*)d_out;

  char* w = (char*)d_ws;
  unsigned short* Abf = (unsigned short*)(w);                // 512 KB bf16 A[j][k]
  float* colsum = (float*)(w + (512 << 10));                 // 2 KB
  float* pi     = (float*)(w + (520 << 10));                 // 2 KB
  float* Pem    = (float*)(w + (1024 << 10));                // 32 MB Pem[t][j][b] fp32

  hipMemsetAsync(colsum, 0, Nn * sizeof(float), stream);
  k_colsum<<<32,  256, 0, stream>>>(trans, colsum);
  k_writeA<<<1024, 256, 0, stream>>>(trans, colsum, Abf);
  k_pi    <<<1,   512, 0, stream>>>(prior, pi);
  k_emis  <<<Nn,  256, 0, stream>>>(emis, x, Pem);
  k_fwd   <<<4,   512, 0, stream>>>(Abf, Pem, pi, Tlen, out);
}

// Round 3
// 465.752 us; speedup vs baseline: 4.9750x; 4.9750x over previous
//
#include <hip/hip_runtime.h>
#include <math.h>

#define Nn 512
#define Mm 32000
#define Bb 64
#define Tt 256

typedef float v4f __attribute__((ext_vector_type(4)));
typedef float f4 __attribute__((ext_vector_type(4)));

// pack 4 f32 -> 4 OCP e4m3 bytes in an int
__device__ inline int pk4fp8(float a, float b, float c, float d) {
  int r = __builtin_amdgcn_cvt_pk_fp8_f32(a, b, 0, false);
  r = __builtin_amdgcn_cvt_pk_fp8_f32(c, d, r, true);
  return r;
}

// ---- colsum[k] = sum_j exp(trans[j][k]); inputs ~N(0,1) so no overflow ----
__global__ void k_colsum(const float* __restrict__ trans, float* __restrict__ colsum) {
  int tid = threadIdx.x;
  int j0 = blockIdx.x * 16;
  float a0 = 0.f, a1 = 0.f;
  for (int r = 0; r < 16; ++r) {
    a0 += __expf(trans[(j0 + r) * Nn + tid]);
    a1 += __expf(trans[(j0 + r) * Nn + 256 + tid]);
  }
  atomicAdd(&colsum[tid], a0);
  atomicAdd(&colsum[256 + tid], a1);
}

// ---- A_s[j][k] = 256*exp(trans[j][k])/colsum[k] as e4m3, row-major packed dwords ----
__global__ void k_writeA8(const float* __restrict__ trans, const float* __restrict__ colsum,
                          int* __restrict__ A8) {
  int d = blockIdx.x * 256 + threadIdx.x;      // 65536 dwords = 512x512 bytes
  int j = d >> 7, k0 = (d & 127) << 2;
  float v0 = 256.f * __expf(trans[j * Nn + k0 + 0]) / colsum[k0 + 0];
  float v1 = 256.f * __expf(trans[j * Nn + k0 + 1]) / colsum[k0 + 1];
  float v2 = 256.f * __expf(trans[j * Nn + k0 + 2]) / colsum[k0 + 2];
  float v3 = 256.f * __expf(trans[j * Nn + k0 + 3]) / colsum[k0 + 3];
  A8[d] = pk4fp8(v0, v1, v2, v3);
}

// ---- pi = softmax(prior) ----
__global__ void k_pi(const float* __restrict__ prior, float* __restrict__ pi) {
  int tid = threadIdx.x;
  __shared__ float sm[512];
  float e = __expf(prior[tid]);
  sm[tid] = e; __syncthreads();
  for (int off = 256; off; off >>= 1) { if (tid < off) sm[tid] += sm[tid + off]; __syncthreads(); }
  pi[tid] = e / sm[0];
}

// ---- Pem_s[t][j][b] = 2^15 * exp(emis[j,x[b,t]]) / rowsum_j ----
__global__ void k_emis(const float* __restrict__ emis, const int* __restrict__ x,
                       float* __restrict__ Pem) {
  int j = blockIdx.x, tid = threadIdx.x;
  const float* row = emis + (size_t)j * Mm;
  const f4* row4 = (const f4*)row;
  float s = 0.f;
  for (int i = tid; i < Mm / 4; i += 256) {
    f4 v = row4[i];
    s += __expf(v.x) + __expf(v.y) + __expf(v.z) + __expf(v.w);
  }
  __shared__ float ss[256];
  ss[tid] = s; __syncthreads();
  for (int off = 128; off; off >>= 1) { if (tid < off) ss[tid] += ss[tid + off]; __syncthreads(); }
  float rs = 32768.f / ss[0];
  for (int r = 0; r < (Bb * Tt) / 256; ++r) {
    int idx = r * 256 + tid;
    int t = idx >> 6, b = idx & 63;
    int mv = x[b * Tt + t];
    Pem[(size_t)t * (Nn * Bb) + j * Bb + b] = __expf(row[mv]) * rs;
  }
}

// ---- recursion: 4 independent blocks (16 batch cols), 8 waves x 64 rows of fp8 A in VGPRs,
// ---- fp8 y ping-pongs in LDS, S via epilogue reduce (no ones-MFMA), 1 barrier/step ----
__global__ __launch_bounds__(512, 2) void k_fwd(
    const char* __restrict__ A8, const float* __restrict__ Pem,
    const float* __restrict__ pi, const int* __restrict__ Tlen,
    float* __restrict__ out)
{
  __shared__ __align__(16) char ybuf[2][16 * Nn];   // fp8 [c][k], XOR-swizzled; 16 KB
  __shared__ float Spart[2][8][16];                 // per-wave column-sum partials
  const int g = blockIdx.x;
  const int tid = threadIdx.x;
  const int w = tid >> 6, lane = tid & 63;
  const int c = lane & 15, kq = lane >> 4;
  const int jw = w * 64;
  const int swz = (c & 7) << 4;
  const int b = g * 16 + c;
  const float C23 = 15.942385152878742f;            // 23*ln2 (scale bookkeeping)

  // A fragments: af[rt][kk] -> lane holds A_s[jw+rt*16+c][kk*32+kq*8 .. +8] (8 fp8 = i64)
  long af[4][16];
  #pragma unroll
  for (int rt = 0; rt < 4; ++rt)
    #pragma unroll
    for (int kk = 0; kk < 16; ++kk)
      af[rt][kk] = *reinterpret_cast<const long*>(A8 + (size_t)(jw + rt * 16 + c) * Nn + kk * 32 + kq * 8);

  const int Tb = Tlen[b];
  float L = 0.f;

  // ---- init: Y0[j][c'] = 2^8 * pi[j] * Pem_s[0][j][c'], plus S partials ----
  if (tid < 256) ((float*)Spart)[tid] = 0.f;
  __syncthreads();
  {
    int cc = tid & 15, grp = tid >> 4, jb = (tid >> 4) * 16, sz = (cc & 7) << 4;
    float psum = 0.f;
    char* yp = &ybuf[0][0];
    #pragma unroll
    for (int q = 0; q < 4; ++q) {
      float v0, v1, v2, v3;
      int j = jb + q * 4;
      v0 = 256.f * pi[j + 0] * Pem[(size_t)(j + 0) * Bb + g * 16 + cc];
      v1 = 256.f * pi[j + 1] * Pem[(size_t)(j + 1) * Bb + g * 16 + cc];
      v2 = 256.f * pi[j + 2] * Pem[(size_t)(j + 2) * Bb + g * 16 + cc];
      v3 = 256.f * pi[j + 3] * Pem[(size_t)(j + 3) * Bb + g * 16 + cc];
      psum += v0 + v1 + v2 + v3;
      *reinterpret_cast<int*>(yp + ((cc * Nn + j) ^ sz)) = pk4fp8(v0, v1, v2, v3);
    }
    atomicAdd(&Spart[0][grp & 7][cc], psum);
  }
  __syncthreads();

  int p = 0;
  for (int t = 1; t <= Tt; ++t) {
    // S_t = sum_k Y_{t-1}[k] (f32 partials from previous epilogue/init)
    float S = Spart[p][0][c] + Spart[p][1][c] + Spart[p][2][c] + Spart[p][3][c]
            + Spart[p][4][c] + Spart[p][5][c] + Spart[p][6][c] + Spart[p][7][c];
    L += __logf(S) - C23;                  // L = log_sums[b][t-1]
    if (w == 0 && kq == 0 && Tb == t) out[b] = L;
    if (t == Tt) break;

    // emission probs for this step (independent of y; hidden under MFMAs)
    float pem[4][4];
    #pragma unroll
    for (int rt = 0; rt < 4; ++rt)
      #pragma unroll
      for (int r = 0; r < 4; ++r)
        pem[rt][r] = Pem[(size_t)t * (Nn * Bb) + (size_t)(jw + rt * 16 + kq * 4 + r) * Bb + b];

    // B fragments from LDS (fp8, swizzled): lane holds Y[kk*32+kq*8 .. +8][c]
    const char* rp = &ybuf[p][0];
    long bfr[16];
    #pragma unroll
    for (int kk = 0; kk < 16; ++kk)
      bfr[kk] = *reinterpret_cast<const long*>(rp + ((c * Nn + kk * 32 + kq * 8) ^ swz));

    v4f a0 = {0.f,0.f,0.f,0.f}, a1 = {0.f,0.f,0.f,0.f};
    v4f a2 = {0.f,0.f,0.f,0.f}, a3 = {0.f,0.f,0.f,0.f};
    #pragma unroll
    for (int kk = 0; kk < 16; ++kk) {
      long bb = bfr[kk];
      a0 = __builtin_amdgcn_mfma_f32_16x16x32_fp8_fp8(af[0][kk], bb, a0, 0, 0, 0);
      a1 = __builtin_amdgcn_mfma_f32_16x16x32_fp8_fp8(af[1][kk], bb, a1, 0, 0, 0);
      a2 = __builtin_amdgcn_mfma_f32_16x16x32_fp8_fp8(af[2][kk], bb, a2, 0, 0, 0);
      a3 = __builtin_amdgcn_mfma_f32_16x16x32_fp8_fp8(af[3][kk], bb, a3, 0, 0, 0);
    }

    // epilogue: Y_t = (A_s Y_{t-1}) .* Pem_s / S_t   (stays in fp8 sweet spot by scaling)
    float inv = 1.f / S;
    char* wp = &ybuf[p ^ 1][0];
    float vsum = 0.f;
    #define EPI(AC, RT) { \
      float v0 = AC[0] * pem[RT][0] * inv, v1 = AC[1] * pem[RT][1] * inv; \
      float v2 = AC[2] * pem[RT][2] * inv, v3 = AC[3] * pem[RT][3] * inv; \
      vsum += (v0 + v1) + (v2 + v3); \
      *reinterpret_cast<int*>(wp + ((c * Nn + jw + RT * 16 + kq * 4) ^ swz)) = pk4fp8(v0, v1, v2, v3); }
    EPI(a0, 0) EPI(a1, 1) EPI(a2, 2) EPI(a3, 3)
    #undef EPI

    // column partial: reduce over kq lanes, one writer per (w,c)
    vsum += __shfl_xor(vsum, 16);
    vsum += __shfl_xor(vsum, 32);
    if (kq == 0) Spart[p ^ 1][w][c] = vsum;

    p ^= 1;
    __syncthreads();
  }
}

extern "C" void kernel_launch(void* const* d_in, const int* in_sizes, int n_in,
                              void* d_out, int out_size, void* d_ws, size_t ws_size,
                              hipStream_t stream) {
  const int*   x     = (const int*)  d_in[0];
  const int*   Tlen  = (const int*)  d_in[1];
  const float* trans = (const float*)d_in[2];
  const float* emis  = (const float*)d_in[3];
  const float* prior = (const float*)d_in[4];
  float* out = (float*)d_out;

  char* w = (char*)d_ws;
  char*  A8     = (char*)(w);                     // 256 KB fp8 A_s[j][k]
  float* colsum = (float*)(w + (512 << 10));      // 2 KB
  float* pi     = (float*)(w + (520 << 10));      // 2 KB
  float* Pem    = (float*)(w + (1024 << 10));     // 32 MB Pem_s[t][j][b] fp32

  hipMemsetAsync(colsum, 0, Nn * sizeof(float), stream);
  k_colsum <<<32,   256, 0, stream>>>(trans, colsum);
  k_writeA8<<<256,  256, 0, stream>>>(trans, colsum, (int*)A8);
  k_pi     <<<1,    512, 0, stream>>>(prior, pi);
  k_emis   <<<Nn,   256, 0, stream>>>(emis, x, Pem);
  k_fwd    <<<4,    512, 0, stream>>>(A8, Pem, pi, Tlen, out);
}

// Round 5
// 430.558 us; speedup vs baseline: 5.3816x; 1.0817x over previous
//
#include <hip/hip_runtime.h>
#include <math.h>

#define Nn 512
#define Mm 32000
#define Bb 64
#define Tt 256

typedef float v4f __attribute__((ext_vector_type(4)));
typedef float f4  __attribute__((ext_vector_type(4)));
typedef int   v4i __attribute__((ext_vector_type(4)));
typedef int   v8i __attribute__((ext_vector_type(8)));

// pack 4 f32 -> 4 OCP e4m3 bytes in an int
__device__ inline int pk4fp8(float a, float b, float c, float d) {
  int r = __builtin_amdgcn_cvt_pk_fp8_f32(a, b, 0, false);
  r = __builtin_amdgcn_cvt_pk_fp8_f32(c, d, r, true);
  return r;
}

// ---- colsum[k] = sum_j exp(trans[j][k]); inputs ~N(0,1) so no overflow ----
__global__ void k_colsum(const float* __restrict__ trans, float* __restrict__ colsum) {
  int tid = threadIdx.x;
  int j0 = blockIdx.x * 16;
  float a0 = 0.f, a1 = 0.f;
  for (int r = 0; r < 16; ++r) {
    a0 += __expf(trans[(j0 + r) * Nn + tid]);
    a1 += __expf(trans[(j0 + r) * Nn + 256 + tid]);
  }
  atomicAdd(&colsum[tid], a0);
  atomicAdd(&colsum[256 + tid], a1);
}

// ---- A_s[j][k] = 256*exp(trans[j][k])/colsum[k] as e4m3, row-major packed dwords ----
__global__ void k_writeA8(const float* __restrict__ trans, const float* __restrict__ colsum,
                          int* __restrict__ A8) {
  int d = blockIdx.x * 256 + threadIdx.x;      // 65536 dwords = 512x512 bytes
  int j = d >> 7, k0 = (d & 127) << 2;
  float v0 = 256.f * __expf(trans[j * Nn + k0 + 0]) / colsum[k0 + 0];
  float v1 = 256.f * __expf(trans[j * Nn + k0 + 1]) / colsum[k0 + 1];
  float v2 = 256.f * __expf(trans[j * Nn + k0 + 2]) / colsum[k0 + 2];
  float v3 = 256.f * __expf(trans[j * Nn + k0 + 3]) / colsum[k0 + 3];
  A8[d] = pk4fp8(v0, v1, v2, v3);
}

// ---- 4 emis rows per block; Pem2[t][g][j>>2][c][j&3] f32, coalesced float4 writes ----
// Pem2[t] = 2^15 * emprob   (t==0 additionally * 2^8 * pi[j])
__global__ void k_emis(const float* __restrict__ emis, const int* __restrict__ x,
                       const float* __restrict__ prior, float* __restrict__ Pem2) {
  int j0 = blockIdx.x * 4, tid = threadIdx.x;
  __shared__ float ss[256];
  __shared__ float fac[2][4];   // [0][q] = rs_q, [1][q] = t0 factor

  // total prior exp-sum (redundant per block, cheap)
  float ps = __expf(prior[tid]) + __expf(prior[tid + 256]);
  ss[tid] = ps; __syncthreads();
  for (int off = 128; off; off >>= 1) { if (tid < off) ss[tid] += ss[tid + off]; __syncthreads(); }
  float ptot = ss[0]; __syncthreads();

  // row sums of exp(emis) for the 4 rows
  for (int q = 0; q < 4; ++q) {
    const f4* row4 = (const f4*)(emis + (size_t)(j0 + q) * Mm);
    float s = 0.f;
    for (int i = tid; i < Mm / 4; i += 256) {
      f4 v = row4[i];
      s += __expf(v[0]) + __expf(v[1]) + __expf(v[2]) + __expf(v[3]);
    }
    ss[tid] = s; __syncthreads();
    for (int off = 128; off; off >>= 1) { if (tid < off) ss[tid] += ss[tid + off]; __syncthreads(); }
    if (tid == 0) {
      float rs = 32768.f / ss[0];
      fac[0][q] = rs;
      fac[1][q] = rs * 256.f * __expf(prior[j0 + q]) / ptot;
    }
    __syncthreads();
  }

  const float* r0 = emis + (size_t)(j0 + 0) * Mm;
  const float* r1 = emis + (size_t)(j0 + 1) * Mm;
  const float* r2 = emis + (size_t)(j0 + 2) * Mm;
  const float* r3 = emis + (size_t)(j0 + 3) * Mm;
  f4* P4 = (f4*)Pem2;
  for (int r = 0; r < (Bb * Tt) / 256; ++r) {
    int idx = r * 256 + tid;
    int t = idx >> 6, b = idx & 63;
    int mv = x[b * Tt + t];
    const float* fq = (t == 0) ? &fac[1][0] : &fac[0][0];
    f4 o;
    o[0] = __expf(r0[mv]) * fq[0];
    o[1] = __expf(r1[mv]) * fq[1];
    o[2] = __expf(r2[mv]) * fq[2];
    o[3] = __expf(r3[mv]) * fq[3];
    P4[t * 8192 + (b >> 4) * 2048 + blockIdx.x * 16 + (b & 15)] = o;
  }
}

// ---- recursion: 4 blocks (16 batch cols), 8 waves x 64 rows of fp8 A in VGPRs,
// ---- MX K=128 MFMA (scales=1.0), fp8 Y ping-pong in LDS, 1 barrier/step ----
__global__ __launch_bounds__(512, 2) void k_fwd(
    const char* __restrict__ A8, const float* __restrict__ Pem2,
    const int* __restrict__ Tlen, float* __restrict__ out)
{
  __shared__ __align__(16) char ybuf[2][16 * Nn];   // fp8 [c][k], XOR-swizzled; 16 KB
  __shared__ __align__(16) float Spart[2][16][12];  // [c][w] partials, padded rows
  const int g = blockIdx.x, tid = threadIdx.x;
  const int w = tid >> 6, lane = tid & 63;
  const int c = lane & 15, kq = lane >> 4;
  const int jw = w * 64;
  const int swz = (c & 7) << 4;
  const int b = g * 16 + c;
  const float C23 = 15.942385152878742f;            // 23*ln2
  const int SC1 = 0x7F;                             // e8m0 = 1.0 in byte 0

  // A fragments: af[rt][kc] -> lane holds A_s[jw+rt*16+c][kc*128 + kq*32 + 0..31]
  v8i af[4][4];
  #pragma unroll
  for (int rt = 0; rt < 4; ++rt)
    #pragma unroll
    for (int kc = 0; kc < 4; ++kc)
      af[rt][kc] = *reinterpret_cast<const v8i*>(
          A8 + (size_t)(jw + rt * 16 + c) * Nn + kc * 128 + kq * 32);

  const int Tb = Tlen[b];
  float L = 0.f;

  // zero Spart[0], init Y0 from Pem2[0] (already includes 2^23 * pi * emprob)
  if (tid < 192) ((float*)&Spart[0][0][0])[tid] = 0.f;
  __syncthreads();
  {
    int cc = tid & 15, grp = tid >> 4, jb = grp * 16, sz = (cc & 7) << 4;
    const f4* P0 = (const f4*)Pem2 + g * 2048 + (jb >> 2) * 16 + cc;
    float psum = 0.f;
    char* yp = &ybuf[0][0];
    #pragma unroll
    for (int q = 0; q < 4; ++q) {
      f4 v = P0[q * 16];
      psum += (v[0] + v[1]) + (v[2] + v[3]);
      *reinterpret_cast<int*>(yp + ((cc * Nn + jb + q * 4) ^ sz)) = pk4fp8(v[0], v[1], v[2], v[3]);
    }
    atomicAdd(&Spart[0][cc][grp & 7], psum);
  }
  __syncthreads();

  // prologue: emission probs for step 1
  const f4* PB = (const f4*)Pem2;
  #define PIDX(T, RT) ((T) * 8192 + g * 2048 + ((jw + (RT) * 16) >> 2) * 16 + kq * 16 + c)
  f4 pem[4];
  #pragma unroll
  for (int rt = 0; rt < 4; ++rt) pem[rt] = PB[PIDX(1, rt)];

  int p = 0;
  for (int t = 1; t <= Tt; ++t) {
    // S = sum_k Y_{t-1}[k,c] from per-wave partials
    f4 s0 = *reinterpret_cast<const f4*>(&Spart[p][c][0]);
    f4 s1 = *reinterpret_cast<const f4*>(&Spart[p][c][4]);
    float S = ((s0[0] + s0[1]) + (s0[2] + s0[3])) + ((s1[0] + s1[1]) + (s1[2] + s1[3]));
    L += __logf(S) - C23;
    if (w == 0 && kq == 0 && Tb == t) out[b] = L;
    if (t == Tt) break;

    // prefetch emission probs for step t+1 (hidden under MFMAs)
    f4 pemN[4];
    bool pf = (t + 1 < Tt);
    if (pf) {
      #pragma unroll
      for (int rt = 0; rt < 4; ++rt) pemN[rt] = PB[PIDX(t + 1, rt)];
    }

    // B fragments from LDS (fp8, swizzled): lane holds Y[kc*128 + kq*32 + 0..31][c]
    const char* rp = &ybuf[p][0];
    v8i bb[4];
    #pragma unroll
    for (int kc = 0; kc < 4; ++kc) {
      int base = c * Nn + kc * 128 + kq * 32;
      v4i lo = *reinterpret_cast<const v4i*>(rp + ((base     ) ^ swz));
      v4i hi = *reinterpret_cast<const v4i*>(rp + ((base + 16) ^ swz));
      bb[kc] = (v8i){lo[0], lo[1], lo[2], lo[3], hi[0], hi[1], hi[2], hi[3]};
    }

    v4f a0 = {0.f,0.f,0.f,0.f}, a1 = {0.f,0.f,0.f,0.f};
    v4f a2 = {0.f,0.f,0.f,0.f}, a3 = {0.f,0.f,0.f,0.f};
    #pragma unroll
    for (int kc = 0; kc < 4; ++kc) {
      a0 = __builtin_amdgcn_mfma_scale_f32_16x16x128_f8f6f4(af[0][kc], bb[kc], a0, 0, 0, 0, SC1, 0, SC1);
      a1 = __builtin_amdgcn_mfma_scale_f32_16x16x128_f8f6f4(af[1][kc], bb[kc], a1, 0, 0, 0, SC1, 0, SC1);
      a2 = __builtin_amdgcn_mfma_scale_f32_16x16x128_f8f6f4(af[2][kc], bb[kc], a2, 0, 0, 0, SC1, 0, SC1);
      a3 = __builtin_amdgcn_mfma_scale_f32_16x16x128_f8f6f4(af[3][kc], bb[kc], a3, 0, 0, 0, SC1, 0, SC1);
    }

    // epilogue: Y_t = (A_s Y_{t-1}) .* Pem_s / S
    float inv = 1.f / S;
    char* wp = &ybuf[p ^ 1][0];
    float vsum = 0.f;
    #define EPI(AC, RT) { \
      float v0 = AC[0] * pem[RT][0] * inv, v1 = AC[1] * pem[RT][1] * inv; \
      float v2 = AC[2] * pem[RT][2] * inv, v3 = AC[3] * pem[RT][3] * inv; \
      vsum += (v0 + v1) + (v2 + v3); \
      *reinterpret_cast<int*>(wp + ((c * Nn + jw + RT * 16 + kq * 4) ^ swz)) = pk4fp8(v0, v1, v2, v3); }
    EPI(a0, 0) EPI(a1, 1) EPI(a2, 2) EPI(a3, 3)
    #undef EPI

    // column partial: reduce over kq lanes, one writer per (w,c)
    vsum += __shfl_xor(vsum, 16);
    vsum += __shfl_xor(vsum, 32);
    if (kq == 0) Spart[p ^ 1][c][w] = vsum;

    if (pf) {
      #pragma unroll
      for (int rt = 0; rt < 4; ++rt) pem[rt] = pemN[rt];
    }
    p ^= 1;
    __syncthreads();
  }
  #undef PIDX
}

extern "C" void kernel_launch(void* const* d_in, const int* in_sizes, int n_in,
                              void* d_out, int out_size, void* d_ws, size_t ws_size,
                              hipStream_t stream) {
  const int*   x     = (const int*)  d_in[0];
  const int*   Tlen  = (const int*)  d_in[1];
  const float* trans = (const float*)d_in[2];
  const float* emis  = (const float*)d_in[3];
  const float* prior = (const float*)d_in[4];
  float* out = (float*)d_out;

  char* w = (char*)d_ws;
  char*  A8     = (char*)(w);                     // 256 KB fp8 A_s[j][k]
  float* colsum = (float*)(w + (512 << 10));      // 2 KB
  float* Pem2   = (float*)(w + (1024 << 10));     // 32 MB Pem2[t][g][j>>2][c][j&3] f32

  hipMemsetAsync(colsum, 0, Nn * sizeof(float), stream);
  k_colsum <<<32,   256, 0, stream>>>(trans, colsum);
  k_writeA8<<<256,  256, 0, stream>>>(trans, colsum, (int*)A8);
  k_emis   <<<Nn/4, 256, 0, stream>>>(emis, x, prior, Pem2);
  k_fwd    <<<4,    512, 0, stream>>>(A8, Pem2, Tlen, out);
}

// Round 6
// 355.896 us; speedup vs baseline: 6.5106x; 1.2098x over previous
//
#include <hip/hip_runtime.h>
#include <math.h>

#define Nn 512
#define Mm 32000
#define Bb 64
#define Tt 256
#define NCONS 4     // consumer (recursion) blocks
#define NPROD 128   // producer (emission) blocks

typedef float v4f __attribute__((ext_vector_type(4)));
typedef float f4  __attribute__((ext_vector_type(4)));
typedef int   v4i __attribute__((ext_vector_type(4)));
typedef int   v8i __attribute__((ext_vector_type(8)));

// pack 4 f32 -> 4 OCP e4m3 bytes in an int
__device__ inline int pk4fp8(float a, float b, float c, float d) {
  int r = __builtin_amdgcn_cvt_pk_fp8_f32(a, b, 0, false);
  r = __builtin_amdgcn_cvt_pk_fp8_f32(c, d, r, true);
  return r;
}

// ---- colsum[k] = sum_j exp(trans[j][k]) ----
__global__ void k_colsum(const float* __restrict__ trans, float* __restrict__ colsum) {
  int tid = threadIdx.x;
  int j0 = blockIdx.x * 16;
  float a0 = 0.f, a1 = 0.f;
  for (int r = 0; r < 16; ++r) {
    a0 += __expf(trans[(j0 + r) * Nn + tid]);
    a1 += __expf(trans[(j0 + r) * Nn + 256 + tid]);
  }
  atomicAdd(&colsum[tid], a0);
  atomicAdd(&colsum[256 + tid], a1);
}

// ---- A_s[j][k] = 256*exp(trans[j][k])/colsum[k] as e4m3 ----
__global__ void k_writeA8(const float* __restrict__ trans, const float* __restrict__ colsum,
                          int* __restrict__ A8) {
  int d = blockIdx.x * 256 + threadIdx.x;
  int j = d >> 7, k0 = (d & 127) << 2;
  float v0 = 256.f * __expf(trans[j * Nn + k0 + 0]) / colsum[k0 + 0];
  float v1 = 256.f * __expf(trans[j * Nn + k0 + 1]) / colsum[k0 + 1];
  float v2 = 256.f * __expf(trans[j * Nn + k0 + 2]) / colsum[k0 + 2];
  float v3 = 256.f * __expf(trans[j * Nn + k0 + 3]) / colsum[k0 + 3];
  A8[d] = pk4fp8(v0, v1, v2, v3);
}

// ---- fused: blocks 0-3 recursion (consumers), blocks 4-131 emission (producers) ----
__global__ __launch_bounds__(512, 2) void k_fused(
    const char* __restrict__ A8, const float* __restrict__ emis,
    const int* __restrict__ x, const float* __restrict__ prior,
    const int* __restrict__ Tlen, float* __restrict__ Pem2,
    int* __restrict__ progress, float* __restrict__ out)
{
  __shared__ __align__(16) char ybuf[2][16 * Nn];   // fp8 [c][k], XOR-swizzled; 16 KB
  __shared__ __align__(16) float Spart[2][16][12];  // [c][w] partials, padded
  __shared__ float ss[512];
  __shared__ float fac[2][4];
  const int tid = threadIdx.x;

  if (blockIdx.x >= NCONS) {
    // ================= producer: 4 emis rows, Pem2 in 32-t chunks =================
    const int p = blockIdx.x - NCONS;     // 0..127 -> rows 4p..4p+3 (j-quad p)
    const int j0 = p * 4;
    float ps = __expf(prior[tid]);
    ss[tid] = ps; __syncthreads();
    for (int off = 256; off; off >>= 1) { if (tid < off) ss[tid] += ss[tid + off]; __syncthreads(); }
    float ptot = ss[0]; __syncthreads();
    for (int q = 0; q < 4; ++q) {
      const f4* row4 = (const f4*)(emis + (size_t)(j0 + q) * Mm);
      float s = 0.f;
      for (int i = tid; i < Mm / 4; i += 512) {
        f4 v = row4[i];
        s += __expf(v[0]) + __expf(v[1]) + __expf(v[2]) + __expf(v[3]);
      }
      ss[tid] = s; __syncthreads();
      for (int off = 256; off; off >>= 1) { if (tid < off) ss[tid] += ss[tid + off]; __syncthreads(); }
      if (tid == 0) {
        float rs = 32768.f / ss[0];
        fac[0][q] = rs;
        fac[1][q] = rs * 256.f * __expf(prior[j0 + q]) / ptot;   // t=0 includes pi
      }
      __syncthreads();
    }
    const float* r0 = emis + (size_t)(j0 + 0) * Mm;
    const float* r1 = emis + (size_t)(j0 + 1) * Mm;
    const float* r2 = emis + (size_t)(j0 + 2) * Mm;
    const float* r3 = emis + (size_t)(j0 + 3) * Mm;
    f4* P4 = (f4*)Pem2;
    for (int c8 = 0; c8 < 8; ++c8) {
      #pragma unroll
      for (int r = 0; r < 4; ++r) {                 // 32t*64b/512thr = 4 iters
        int idx = c8 * 2048 + r * 512 + tid;
        int t = idx >> 6, b = idx & 63;
        int mv = x[b * Tt + t];
        const float* fq = (t == 0) ? &fac[1][0] : &fac[0][0];
        f4 o;
        o[0] = __expf(r0[mv]) * fq[0]; o[1] = __expf(r1[mv]) * fq[1];
        o[2] = __expf(r2[mv]) * fq[2]; o[3] = __expf(r3[mv]) * fq[3];
        P4[t * 8192 + (b >> 4) * 2048 + p * 16 + (b & 15)] = o;
      }
      __syncthreads();                              // all stores drained to L2
      if (tid == 0) {
        __builtin_amdgcn_fence(__ATOMIC_RELEASE, "agent");   // wb L2 -> coherence point
        __hip_atomic_fetch_add(&progress[c8], 1, __ATOMIC_RELAXED, __HIP_MEMORY_SCOPE_AGENT);
      }
    }
    return;
  }

  // ================= consumer: recursion on 16 batch cols =================
  const int g = blockIdx.x;
  const int w = tid >> 6, lane = tid & 63;
  const int c = lane & 15, kq = lane >> 4;
  const int jw = w * 64;
  const int swz = (c & 7) << 4;
  const int b = g * 16 + c;

  // A fragments: lane holds A_s[jw+rt*16+c][kc*128 + kq*32 + 0..31]
  v8i af[4][4];
  #pragma unroll
  for (int rt = 0; rt < 4; ++rt)
    #pragma unroll
    for (int kc = 0; kc < 4; ++kc)
      af[rt][kc] = *reinterpret_cast<const v8i*>(
          A8 + (size_t)(jw + rt * 16 + c) * Nn + kc * 128 + kq * 32);

  const int Tb = Tlen[b];
  int E = 23;          // Y = 2^E * alpha (exact integer scale bookkeeping)
  int csafe = 0;       // chunks [0, csafe) published & acquired

  #define ENSURE(NEED)                                                                      \
    while (csafe <= (NEED)) {                                                               \
      if (__hip_atomic_load(&progress[csafe], __ATOMIC_RELAXED,                             \
                            __HIP_MEMORY_SCOPE_AGENT) >= NPROD) {                           \
        ++csafe;                                                                            \
        __builtin_amdgcn_fence(__ATOMIC_ACQUIRE, "agent");                                  \
      } else __builtin_amdgcn_s_sleep(2);                                                   \
    }

  // hoisted swizzled LDS byte offsets (buffer 0 relative)
  int roA[4], roB[4], wof[4];
  #pragma unroll
  for (int kc = 0; kc < 4; ++kc) {
    int base = c * Nn + kc * 128 + kq * 32;
    roA[kc] = base ^ swz;
    roB[kc] = (base + 16) ^ swz;
  }
  #pragma unroll
  for (int rt = 0; rt < 4; ++rt)
    wof[rt] = (c * Nn + jw + rt * 16 + kq * 4) ^ swz;
  char* const yb0 = &ybuf[0][0];

  if (tid < 192) ((float*)&Spart[0][0][0])[tid] = 0.f;
  __syncthreads();

  ENSURE(0);                                       // Pem2[0..31] ready

  // init: Y0 = Pem2[0] (includes 2^23 * pi * emprob)
  {
    int cc = tid & 15, grp = tid >> 4, jb = grp * 16, sz = (cc & 7) << 4;
    const f4* P0 = (const f4*)Pem2 + g * 2048 + (jb >> 2) * 16 + cc;
    float psum = 0.f;
    #pragma unroll
    for (int q = 0; q < 4; ++q) {
      f4 v = P0[q * 16];
      psum += (v[0] + v[1]) + (v[2] + v[3]);
      *reinterpret_cast<int*>(yb0 + ((cc * Nn + jb + q * 4) ^ sz)) = pk4fp8(v[0], v[1], v[2], v[3]);
    }
    atomicAdd(&Spart[0][cc][grp & 7], psum);
  }
  __syncthreads();

  const f4* PB = (const f4*)Pem2;
  #define PIDX(T, RT) ((T) * 8192 + g * 2048 + ((jw + (RT) * 16) >> 2) * 16 + kq * 16 + c)
  f4 pem[4];
  #pragma unroll
  for (int rt = 0; rt < 4; ++rt) pem[rt] = PB[PIDX(1, rt)];

  int pp = 0;                                       // LDS buffer byte toggle (0/8192)
  for (int t = 1; t <= Tt; ++t) {
    int sp = pp >> 13;
    f4 s0 = *reinterpret_cast<const f4*>(&Spart[sp][c][0]);
    f4 s1 = *reinterpret_cast<const f4*>(&Spart[sp][c][4]);
    float S = ((s0[0] + s0[1]) + (s0[2] + s0[3])) + ((s1[0] + s1[1]) + (s1[2] + s1[3]));
    int expb = (int)((__float_as_uint(S) >> 23) & 0xFF);
    if (w == 0 && kq == 0 && Tb == t) out[b] = __logf(S) - (float)E * 0.69314718056f;
    if (t == Tt) break;
    E += 150 - expb;                                // E += 23 - (expb-127)
    float scl = __uint_as_float((unsigned)(254 - expb) << 23);   // 2^-(ilogb S)

    bool pf = (t + 1 < Tt);
    if (pf && (((t + 1) & 31) == 0)) ENSURE((t + 1) >> 5);
    f4 pemN[4];
    if (pf) {
      #pragma unroll
      for (int rt = 0; rt < 4; ++rt) pemN[rt] = PB[PIDX(t + 1, rt)];
    }

    // B fragments from LDS (fp8, swizzled)
    const char* rp = yb0 + pp;
    union BU { v8i v; v4i h[2]; };
    BU bu[4];
    #pragma unroll
    for (int kc = 0; kc < 4; ++kc) {
      bu[kc].h[0] = *reinterpret_cast<const v4i*>(rp + roA[kc]);
      bu[kc].h[1] = *reinterpret_cast<const v4i*>(rp + roB[kc]);
    }

    v4f a0 = {0.f,0.f,0.f,0.f}, a1 = {0.f,0.f,0.f,0.f};
    v4f a2 = {0.f,0.f,0.f,0.f}, a3 = {0.f,0.f,0.f,0.f};
    #pragma unroll
    for (int kc = 0; kc < 4; ++kc) {
      v8i bbv = bu[kc].v;
      a0 = __builtin_amdgcn_mfma_scale_f32_16x16x128_f8f6f4(af[0][kc], bbv, a0, 0, 0, 0, 0x7F, 0, 0x7F);
      a1 = __builtin_amdgcn_mfma_scale_f32_16x16x128_f8f6f4(af[1][kc], bbv, a1, 0, 0, 0, 0x7F, 0, 0x7F);
      a2 = __builtin_amdgcn_mfma_scale_f32_16x16x128_f8f6f4(af[2][kc], bbv, a2, 0, 0, 0, 0x7F, 0, 0x7F);
      a3 = __builtin_amdgcn_mfma_scale_f32_16x16x128_f8f6f4(af[3][kc], bbv, a3, 0, 0, 0, 0x7F, 0, 0x7F);
    }

    // epilogue: Y_t = (A_s Y_{t-1}) .* pem .* 2^-e   (power-2 normalization)
    char* wp = yb0 + (pp ^ 8192);
    float vsum = 0.f;
    #define EPI(AC, RT) {                                                     \
      float v0 = AC[0] * (pem[RT][0] * scl), v1 = AC[1] * (pem[RT][1] * scl); \
      float v2 = AC[2] * (pem[RT][2] * scl), v3 = AC[3] * (pem[RT][3] * scl); \
      vsum += (v0 + v1) + (v2 + v3);                                          \
      *reinterpret_cast<int*>(wp + wof[RT]) = pk4fp8(v0, v1, v2, v3); }
    EPI(a0, 0) EPI(a1, 1) EPI(a2, 2) EPI(a3, 3)
    #undef EPI

    vsum += __shfl_xor(vsum, 16);
    vsum += __shfl_xor(vsum, 32);
    if (kq == 0) Spart[sp ^ 1][c][w] = vsum;

    if (pf) {
      #pragma unroll
      for (int rt = 0; rt < 4; ++rt) pem[rt] = pemN[rt];
    }
    pp ^= 8192;
    __syncthreads();
  }
  #undef PIDX
  #undef ENSURE
}

extern "C" void kernel_launch(void* const* d_in, const int* in_sizes, int n_in,
                              void* d_out, int out_size, void* d_ws, size_t ws_size,
                              hipStream_t stream) {
  const int*   x     = (const int*)  d_in[0];
  const int*   Tlen  = (const int*)  d_in[1];
  const float* trans = (const float*)d_in[2];
  const float* emis  = (const float*)d_in[3];
  const float* prior = (const float*)d_in[4];
  float* out = (float*)d_out;

  char* w = (char*)d_ws;
  char*  A8       = (char*)(w);                     // 256 KB fp8 A_s[j][k]
  float* colsum   = (float*)(w + (512 << 10));      // 2 KB
  int*   progress = (int*)  (w + (512 << 10) + 4096);  // 8 chunk counters
  float* Pem2     = (float*)(w + (1024 << 10));     // 32 MB Pem2[t][g][j>>2][c][j&3] f32

  hipMemsetAsync(w + (512 << 10), 0, 8192, stream); // colsum + progress
  k_colsum <<<32,        256, 0, stream>>>(trans, colsum);
  k_writeA8<<<256,       256, 0, stream>>>(trans, colsum, (int*)A8);
  k_fused  <<<NCONS + NPROD, 512, 0, stream>>>(A8, emis, x, prior, Tlen, Pem2, progress, out);
}